// Round 7
// baseline (381.312 us; speedup 1.0000x reference)
//
#include <hip/hip_runtime.h>
#include <hip/hip_bf16.h>
#include <math.h>

constexpr int BB  = 2;
constexpr int NN  = 1220;
constexpr int DKV = 256;
constexpr int H0  = 512, W0 = 512;
constexpr int HH  = 128, WW = 128;
constexpr int HW  = HH * WW;      // 16384
constexpr int KT  = 512;
constexpr int MR  = BB * NN;      // 2440
constexpr int MPAD = 2560;        // 20 * 128

typedef __attribute__((ext_vector_type(8)))  short bf16x8;
typedef __attribute__((ext_vector_type(4)))  float f32x4;
typedef __attribute__((ext_vector_type(16))) float f32x16;

// ---- workspace byte offsets (256-aligned) ----
constexpr size_t B_BEV   = 0;            // f32 bev [B][C][HW] : 33,554,432
constexpr size_t B_SCORE = 33554432;     // f32 score          : 131,072
constexpr size_t B_IDX   = 33685504;     // int idx            : 4,096
constexpr size_t B_WBF   = 33689600;     // bf16 weights       : 3,670,016
constexpr size_t B_KV    = 37359616;     // kv bf16 [1024][256]: 524,288
constexpr size_t B_KG    = 37883904;     // K bf16 [1024][512] : 1,048,576
constexpr size_t B_VG    = 38932480;     // V bf16             : 1,048,576
constexpr size_t B_VT    = 39981056;     // V^T bf16 [2][8][64][512]
constexpr size_t B_H1    = 41029632;     // h1 bf16 [2560][512]
constexpr size_t B_QI32  = 43651072;     // qi f32 [2560][512]
constexpr size_t B_QI16  = 48893952;     // qi bf16
constexpr size_t B_QUERY = 51515392;     // LN(qi) bf16
constexpr size_t B_QG    = 54136832;     // Q bf16 (pre-scaled)
constexpr size_t B_CTX   = 56758272;     // ctx bf16
constexpr size_t B_AO    = 59379712;     // ao bf16
constexpr size_t B_OPO   = 62001152;     // opo f32
constexpr size_t B_LC    = 67244032;     // lc f32
constexpr size_t B_G1    = 72486912;     // g1 bf16
constexpr size_t WS_NEED = 75112448;

constexpr size_t WO_QW = 0, WO_KW = 262144, WO_VW = 393216, WO_AOW = 524288,
                 WO_OPW = 786432, WO_APW2 = 1048576, WO_GW1 = 1310720, WO_GW2 = 1572864;

__device__ __forceinline__ void gload_lds16(void* lds, const void* g) {
  __builtin_amdgcn_global_load_lds((const __attribute__((address_space(1))) unsigned int*)g,
                                   (__attribute__((address_space(3))) unsigned int*)lds, 16, 0, 0);
}

__device__ __forceinline__ unsigned cvt_pk_bf16(float a, float b) {
  unsigned r;
  asm("v_cvt_pk_bf16_f32 %0, %1, %2" : "=v"(r) : "v"(a), "v"(b));
  return r;
}

// ---------------- weight f32 -> bf16 ----------------
__global__ __launch_bounds__(256) void wconv_kernel(
    const float* __restrict__ qw, const float* __restrict__ kw,
    const float* __restrict__ vw, const float* __restrict__ aow,
    const float* __restrict__ opw, const float* __restrict__ apw2,
    const float* __restrict__ gw1, const float* __restrict__ gw2,
    __hip_bfloat16* __restrict__ dst) {
  int i = blockIdx.x * 256 + threadIdx.x;      // < 1835008
  const float* src; int off;
  if (i < 262144)       { src = qw;   off = 0; }
  else if (i < 393216)  { src = kw;   off = 262144; }
  else if (i < 524288)  { src = vw;   off = 393216; }
  else if (i < 786432)  { src = aow;  off = 524288; }
  else if (i < 1048576) { src = opw;  off = 786432; }
  else if (i < 1310720) { src = apw2; off = 1048576; }
  else if (i < 1572864) { src = gw1;  off = 1310720; }
  else                  { src = gw2;  off = 1572864; }
  dst[i] = __float2bfloat16(src[i - off]);
}

// ---------------- avg_pool2d 4x4 (EXACT R3) ----------------
__global__ __launch_bounds__(256) void pool_kernel(const float* __restrict__ pts,
                                                   float* __restrict__ bev) {
  int o = blockIdx.x * 256 + threadIdx.x;
  int w  = o & (WW - 1);
  int h  = (o >> 7) & (HH - 1);
  int bc = o >> 14;
  const float* p = pts + ((bc * H0) + h * 4) * W0 + w * 4;
  float s = 0.f;
#pragma unroll
  for (int r = 0; r < 4; ++r) {
    float4 v = *(const float4*)(p + r * W0);
    s += v.x + v.y + v.z + v.w;
  }
  bev[o] = s * (1.f / 16.f);
}

// ---------------- score (EXACT R3) ----------------
__global__ __launch_bounds__(256) void score_kernel(const float* __restrict__ bev,
                                                    float* __restrict__ score) {
  int t = blockIdx.x * 256 + threadIdx.x;
  int b = t >> 14, p = t & (HW - 1);
  const float* base = bev + (size_t)(b * DKV) * HW + p;
  float acc = 0.f;
  for (int c = 0; c < DKV; ++c) {
    float v = base[c * HW];
    acc += v * v;
  }
  score[t] = acc * (1.f / DKV);
}

// ---------------- top-K set, radix select (EXACT R3: serial tie-walk) ----------
__global__ __launch_bounds__(1024) void topk_kernel(const float* __restrict__ score,
                                                    int* __restrict__ idx) {
  int b = blockIdx.x;
  const float* s = score + b * HW;
  __shared__ int hist[16][256];
  __shared__ int htot[256];
  __shared__ int sh_digit, sh_need, sh_cnt;
  int tid = threadIdx.x;
  int wv = tid >> 6;
  unsigned prefix = 0;
  int need = KT;
  for (int pass = 0; pass < 4; ++pass) {
    int shift = 24 - pass * 8;
    if (tid < 256) {
#pragma unroll
      for (int w = 0; w < 16; ++w) hist[w][tid] = 0;
    }
    __syncthreads();
    for (int p = tid; p < HW; p += 1024) {
      unsigned u = __float_as_uint(s[p]);
      bool match = (pass == 0) || ((u >> (shift + 8)) == prefix);
      if (match) atomicAdd(&hist[wv][(u >> shift) & 255], 1);
    }
    __syncthreads();
    if (tid < 256) {
      int t = 0;
#pragma unroll
      for (int w = 0; w < 16; ++w) t += hist[w][tid];
      htot[tid] = t;
    }
    __syncthreads();
    for (int off = 1; off < 256; off <<= 1) {
      int v = 0;
      if (tid < 256) v = htot[tid] + ((tid + off < 256) ? htot[tid + off] : 0);
      __syncthreads();
      if (tid < 256) htot[tid] = v;
      __syncthreads();
    }
    if (tid < 256) {
      int sfx = htot[tid], sfx1 = (tid < 255) ? htot[tid + 1] : 0;
      if (sfx >= need && sfx1 < need) { sh_digit = tid; sh_need = need - sfx1; }
    }
    __syncthreads();
    prefix = (prefix << 8) | (unsigned)sh_digit;
    need = sh_need;
    __syncthreads();
  }
  unsigned T = prefix;
  int r = need;
  if (tid == 0) sh_cnt = 0;
  __syncthreads();
  for (int p = tid; p < HW; p += 1024) {
    if (__float_as_uint(s[p]) > T) {
      int pos = atomicAdd(&sh_cnt, 1);
      idx[b * KT + pos] = p;
    }
  }
  __syncthreads();
  int base = sh_cnt;                         // == KT - r
  if (tid < 64) {
    int taken = 0;
    for (int c0 = 0; c0 < HW && taken < r; c0 += 64) {
      int p = c0 + tid;
      bool eq = (__float_as_uint(s[p]) == T);
      unsigned long long m = __ballot(eq);
      int rank = __popcll(m & ((1ull << tid) - 1ull));
      if (eq && (taken + rank) < r) idx[b * KT + base + taken + rank] = p;
      taken += __popcll(m);
    }
  }
}

// ---------------- token gather + bev_pos_mlp + LN(tn) -> kv bf16 ----------------
__global__ __launch_bounds__(256) void token_kernel(const float* __restrict__ bev,
    const int* __restrict__ idx,
    const float* __restrict__ bw1, const float* __restrict__ bb1,
    const float* __restrict__ bw2, const float* __restrict__ bb2,
    const float* __restrict__ tw, const float* __restrict__ tb,
    __hip_bfloat16* __restrict__ kv) {
  int blk = blockIdx.x;
  int b = blk >> 9;
  int c = threadIdx.x;
  int p = idx[blk];
  float val = bev[((size_t)(b * DKV + c) << 14) + p];
  float px = ((p & (WW - 1)) + 0.5f) * (1.f / WW);
  float py = ((p >> 7) + 0.5f) * (1.f / HH);
  __shared__ float h1[DKV];
  __shared__ float red[DKV];
  h1[c] = fmaxf(bw1[c * 2] * px + bw1[c * 2 + 1] * py + bb1[c], 0.f);
  __syncthreads();
  float o = bb2[c];
  const float4* w4 = (const float4*)(bw2 + c * DKV);
#pragma unroll 4
  for (int j = 0; j < DKV / 4; ++j) {
    float4 w = w4[j];
    o += w.x * h1[j * 4] + w.y * h1[j * 4 + 1] + w.z * h1[j * 4 + 2] + w.w * h1[j * 4 + 3];
  }
  float tokv = val + o;
  red[c] = tokv; __syncthreads();
  for (int st = 128; st > 0; st >>= 1) { if (c < st) red[c] += red[c + st]; __syncthreads(); }
  float mean = red[0] * (1.f / DKV);
  __syncthreads();
  float d = tokv - mean;
  red[c] = d * d; __syncthreads();
  for (int st = 128; st > 0; st >>= 1) { if (c < st) red[c] += red[c + st]; __syncthreads(); }
  float inv = rsqrtf(red[0] * (1.f / DKV) + 1e-5f);
  kv[(size_t)blk * DKV + c] = __float2bfloat16(d * inv * tw[c] + tb[c]);
}

// ---------------- anchor xy + ap layer1 (relu) -> bf16 ----------------
__global__ __launch_bounds__(256) void ap1_kernel(const float* __restrict__ anchor,
    const float* __restrict__ w1, const float* __restrict__ b1,
    __hip_bfloat16* __restrict__ h) {
  int g = blockIdx.x * 256 + threadIdx.x;
  int row = g >> 9, col = g & 511;
  float ax = anchor[row * 11 + 0];
  float ay = anchor[row * 11 + 1];
  float xr = fminf(fmaxf((ax + 51.2f) * (1.f / 102.4f), 0.f), 1.f);
  float yr = fminf(fmaxf((ay + 51.2f) * (1.f / 102.4f), 0.f), 1.f);
  h[g] = __float2bfloat16(fmaxf(w1[col * 2] * xr + w1[col * 2 + 1] * yr + b1[col], 0.f));
}

// ---------------- MFMA GEMM: C = A(bf16) @ W(bf16)^T + bias ----------------
// BM=128, BN=64, BK=64, 4 waves; double-buffered LDS (THE single new element).
template <int EPI>
__global__ __launch_bounds__(256) void mgemm(
    const short* __restrict__ A, const short* __restrict__ W,
    const float* __restrict__ bias, const float* __restrict__ aux1,
    const float* __restrict__ aux2, void* __restrict__ o1, void* __restrict__ o2,
    int M, int Nd, int Kd) {
  __shared__ short As[2][128 * 64];
  __shared__ short Bs[2][64 * 64];
  const int tid = threadIdx.x;
  const int wave = tid >> 6, lane = tid & 63;
  const int m0 = blockIdx.y * 128, n0 = blockIdx.x * 64;
  const int srow = lane >> 3, sslot = lane & 7;
  const int ss = sslot ^ srow;              // involution swizzle on 16B slots
  f32x4 acc[2][4];
#pragma unroll
  for (int i = 0; i < 2; ++i)
#pragma unroll
    for (int j = 0; j < 4; ++j) acc[i][j] = (f32x4){0.f, 0.f, 0.f, 0.f};

  const short* Abase = A + (size_t)(m0 + srow) * Kd + ss * 8;
  const short* Wbase = W + (size_t)(n0 + srow) * Kd + ss * 8;
  const int nk = Kd >> 6;

#define STAGE(buf, k0)                                                        \
  {                                                                           \
    _Pragma("unroll")                                                         \
    for (int u = 0; u < 4; ++u) {                                             \
      int unit = wave * 4 + u;                                                \
      gload_lds16(&As[buf][unit * 512], Abase + (size_t)(unit * 8) * Kd + (k0)); \
    }                                                                         \
    _Pragma("unroll")                                                         \
    for (int u = 0; u < 2; ++u) {                                             \
      int unit = wave * 2 + u;                                                \
      gload_lds16(&Bs[buf][unit * 512], Wbase + (size_t)(unit * 8) * Kd + (k0)); \
    }                                                                         \
  }

  STAGE(0, 0);
  __syncthreads();
  for (int t = 0; t < nk; ++t) {
    if (t + 1 < nk) STAGE((t + 1) & 1, (t + 1) << 6);
    const short* as = As[t & 1];
    const short* bs = Bs[t & 1];
#pragma unroll
    for (int ks = 0; ks < 2; ++ks) {
      bf16x8 af[2], bf[4];
#pragma unroll
      for (int mf = 0; mf < 2; ++mf) {
        int rr = wave * 32 + mf * 16 + (lane & 15);
        int slot = (ks * 4 + (lane >> 4)) ^ (rr & 7);
        af[mf] = *(const bf16x8*)(as + rr * 64 + slot * 8);
      }
#pragma unroll
      for (int nf = 0; nf < 4; ++nf) {
        int rr = nf * 16 + (lane & 15);
        int slot = (ks * 4 + (lane >> 4)) ^ (rr & 7);
        bf[nf] = *(const bf16x8*)(bs + rr * 64 + slot * 8);
      }
#pragma unroll
      for (int mf = 0; mf < 2; ++mf)
#pragma unroll
        for (int nf = 0; nf < 4; ++nf)
          acc[mf][nf] = __builtin_amdgcn_mfma_f32_16x16x32_bf16(af[mf], bf[nf], acc[mf][nf], 0, 0, 0);
    }
    __syncthreads();
  }
#undef STAGE
#pragma unroll
  for (int mf = 0; mf < 2; ++mf)
#pragma unroll
    for (int nf = 0; nf < 4; ++nf) {
      int col = n0 + nf * 16 + (lane & 15);
      float bv = bias[col];
#pragma unroll
      for (int i = 0; i < 4; ++i) {
        int row = m0 + wave * 32 + mf * 16 + (lane >> 4) * 4 + i;
        if (row < M) {
          float v = acc[mf][nf][i] + bv;
          size_t off = (size_t)row * Nd + col;
          if (EPI == 0) ((__hip_bfloat16*)o1)[off] = __float2bfloat16(v);
          else if (EPI == 1) {
            v += aux1[off];
            ((float*)o1)[off] = v;
            ((__hip_bfloat16*)o2)[off] = __float2bfloat16(v);
          } else if (EPI == 2) ((__hip_bfloat16*)o1)[off] = __float2bfloat16(fmaxf(v, 0.f));
          else if (EPI == 3) ((__hip_bfloat16*)o1)[off] = __float2bfloat16(v * 0.125f);
          else if (EPI == 4) ((float*)o1)[off] = v;
          else if (EPI == 5) {
            float g = 1.f / (1.f + __expf(-v));
            ((float*)o1)[off] = aux1[off] + g * aux2[off];
          }
        }
      }
    }
}

// ---------------- LayerNorm D=512 ----------------
template <int OUT_BF16>
__global__ __launch_bounds__(256) void ln512_kernel(const float* __restrict__ in,
    void* __restrict__ outp, const float* __restrict__ w, const float* __restrict__ bb) {
  int row = blockIdx.x, tid = threadIdx.x;
  float x0 = in[(size_t)row * 512 + tid];
  float x1 = in[(size_t)row * 512 + 256 + tid];
  __shared__ float rs[256], rq[256];
  rs[tid] = x0 + x1;
  rq[tid] = x0 * x0 + x1 * x1;
  __syncthreads();
  for (int o = 128; o > 0; o >>= 1) {
    if (tid < o) { rs[tid] += rs[tid + o]; rq[tid] += rq[tid + o]; }
    __syncthreads();
  }
  float mean = rs[0] * (1.f / 512.f);
  float var = rq[0] * (1.f / 512.f) - mean * mean;
  float inv = rsqrtf(var + 1e-5f);
  float y0 = (x0 - mean) * inv * w[tid] + bb[tid];
  float y1 = (x1 - mean) * inv * w[256 + tid] + bb[256 + tid];
  if (OUT_BF16) {
    ((__hip_bfloat16*)outp)[(size_t)row * 512 + tid] = __float2bfloat16(y0);
    ((__hip_bfloat16*)outp)[(size_t)row * 512 + 256 + tid] = __float2bfloat16(y1);
  } else {
    ((float*)outp)[(size_t)row * 512 + tid] = y0;
    ((float*)outp)[(size_t)row * 512 + 256 + tid] = y1;
  }
}

// ---------------- V transpose: [b*512+t][h*64+d] -> [b][h][d][t] ----------------
__global__ __launch_bounds__(256) void vtrans_kernel(const short* __restrict__ V,
                                                     short* __restrict__ Vt) {
  __shared__ short tile[128][72];
  int tc = blockIdx.x, h = blockIdx.y, b = blockIdx.z;
  int tid = threadIdx.x;
#pragma unroll
  for (int it = 0; it < 8; ++it) {
    int e = it * 256 + tid;
    int r = e >> 4, c = (e & 15) * 4;
    *(short4*)&tile[r][c] =
        *(const short4*)(V + ((size_t)(b * 512 + tc * 128 + r)) * 512 + h * 64 + c);
  }
  __syncthreads();
#pragma unroll
  for (int it = 0; it < 8; ++it) {
    int e = it * 256 + tid;
    int d = e >> 5, t4 = (e & 31) * 4;
    short4 v;
    v.x = tile[t4 + 0][d]; v.y = tile[t4 + 1][d];
    v.z = tile[t4 + 2][d]; v.w = tile[t4 + 3][d];
    *(short4*)(Vt + (((size_t)(b * 8 + h)) * 64 + d) * 512 + tc * 128 + t4) = v;
  }
}

// ---------------- flash attention (EXACT R3 launch: 4 waves/block) ----------------
__global__ __launch_bounds__(256) void attn_kernel(
    const short* __restrict__ Qg, const short* __restrict__ Kg,
    const short* __restrict__ Vt, __hip_bfloat16* __restrict__ ctx) {
  int tid = threadIdx.x;
  int wid = blockIdx.x * 4 + (tid >> 6);     // 0..623
  int lane = tid & 63;
  int l31 = lane & 31, lhi = lane >> 5;
  int qc = wid % 39;
  int bh = wid / 39;
  int h = bh & 7, b = bh >> 3;
  int n = qc * 32 + l31;
  size_t qrow = (size_t)b * NN + n;          // < MPAD
  const short* qp = Qg + qrow * 512 + h * 64 + lhi * 8;
  bf16x8 qf0 = *(const bf16x8*)(qp);
  bf16x8 qf1 = *(const bf16x8*)(qp + 16);
  bf16x8 qf2 = *(const bf16x8*)(qp + 32);
  bf16x8 qf3 = *(const bf16x8*)(qp + 48);
  f32x16 ot0 = {}, ot1 = {};
  float m_run = -1e30f, lsum = 0.f;
  const short* kbase = Kg + ((size_t)(b * KT) + l31) * 512 + h * 64 + lhi * 8;
  const short* vbase = Vt + (((size_t)(b * 8 + h)) * 64 + l31) * 512 + lhi * 8;
  for (int tc = 0; tc < 16; ++tc) {
    const short* kp = kbase + (size_t)(tc * 32) * 512;
    bf16x8 kf0 = *(const bf16x8*)(kp);
    bf16x8 kf1 = *(const bf16x8*)(kp + 16);
    bf16x8 kf2 = *(const bf16x8*)(kp + 32);
    bf16x8 kf3 = *(const bf16x8*)(kp + 48);
    const short* vp = vbase + tc * 32;
    bf16x8 v00 = *(const bf16x8*)(vp);
    bf16x8 v01 = *(const bf16x8*)(vp + 16);
    bf16x8 v10 = *(const bf16x8*)(vp + 32 * 512);
    bf16x8 v11 = *(const bf16x8*)(vp + 32 * 512 + 16);
    f32x16 s = {};
    s = __builtin_amdgcn_mfma_f32_32x32x16_bf16(kf0, qf0, s, 0, 0, 0);
    s = __builtin_amdgcn_mfma_f32_32x32x16_bf16(kf1, qf1, s, 0, 0, 0);
    s = __builtin_amdgcn_mfma_f32_32x32x16_bf16(kf2, qf2, s, 0, 0, 0);
    s = __builtin_amdgcn_mfma_f32_32x32x16_bf16(kf3, qf3, s, 0, 0, 0);
    float pmax = s[0];
#pragma unroll
    for (int i = 1; i < 16; ++i) pmax = fmaxf(pmax, s[i]);
    pmax = fmaxf(pmax, __shfl_xor(pmax, 32));
    float m_new = fmaxf(m_run, pmax);
    float corr = __expf(m_run - m_new);
    m_run = m_new;
    lsum *= corr;
#pragma unroll
    for (int i = 0; i < 16; ++i) { ot0[i] *= corr; ot1[i] *= corr; }
    float p[16];
    float psum = 0.f;
#pragma unroll
    for (int i = 0; i < 16; ++i) { p[i] = __expf(s[i] - m_new); psum += p[i]; }
    lsum += psum;
    unsigned w0 = cvt_pk_bf16(p[0], p[1]),   w1 = cvt_pk_bf16(p[2], p[3]);
    unsigned w2 = cvt_pk_bf16(p[4], p[5]),   w3 = cvt_pk_bf16(p[6], p[7]);
    unsigned w4 = cvt_pk_bf16(p[8], p[9]),   w5 = cvt_pk_bf16(p[10], p[11]);
    unsigned w6 = cvt_pk_bf16(p[12], p[13]), w7 = cvt_pk_bf16(p[14], p[15]);
    unsigned sw0 = (unsigned)__shfl_xor((int)w0, 32), sw1 = (unsigned)__shfl_xor((int)w1, 32);
    unsigned sw2 = (unsigned)__shfl_xor((int)w2, 32), sw3 = (unsigned)__shfl_xor((int)w3, 32);
    unsigned sw4 = (unsigned)__shfl_xor((int)w4, 32), sw5 = (unsigned)__shfl_xor((int)w5, 32);
    unsigned sw6 = (unsigned)__shfl_xor((int)w6, 32), sw7 = (unsigned)__shfl_xor((int)w7, 32);
    union UU { unsigned u[4]; bf16x8 v; };
    UU ub0, ub1;
    ub0.u[0] = lhi ? sw2 : w0; ub0.u[1] = lhi ? sw3 : w1;
    ub0.u[2] = lhi ? w2 : sw0; ub0.u[3] = lhi ? w3 : sw1;
    ub1.u[0] = lhi ? sw6 : w4; ub1.u[1] = lhi ? sw7 : w5;
    ub1.u[2] = lhi ? w6 : sw4; ub1.u[3] = lhi ? w7 : sw5;
    ot0 = __builtin_amdgcn_mfma_f32_32x32x16_bf16(v00, ub0.v, ot0, 0, 0, 0);
    ot0 = __builtin_amdgcn_mfma_f32_32x32x16_bf16(v01, ub1.v, ot0, 0, 0, 0);
    ot1 = __builtin_amdgcn_mfma_f32_32x32x16_bf16(v10, ub0.v, ot1, 0, 0, 0);
    ot1 = __builtin_amdgcn_mfma_f32_32x32x16_bf16(v11, ub1.v, ot1, 0, 0, 0);
  }
  lsum += __shfl_xor(lsum, 32);
  float inv = 1.f / lsum;
  if (n < NN) {
    __hip_bfloat16* cp = ctx + qrow * 512 + h * 64;
#pragma unroll
    for (int r = 0; r < 16; ++r) {
      int d = (r & 3) + 8 * (r >> 2) + 4 * lhi;
      cp[d]      = __float2bfloat16(ot0[r] * inv);
      cp[32 + d] = __float2bfloat16(ot1[r] * inv);
    }
  }
}

extern "C" void kernel_launch(void* const* d_in, const int* in_sizes, int n_in,
                              void* d_out, int out_size, void* d_ws, size_t ws_size,
                              hipStream_t stream) {
  const float* inst   = (const float*)d_in[0];
  const float* pts    = (const float*)d_in[1];
  const float* anchor = (const float*)d_in[2];
  const float* qw  = (const float*)d_in[3];
  const float* qb  = (const float*)d_in[4];
  const float* kw  = (const float*)d_in[5];
  const float* kb  = (const float*)d_in[6];
  const float* vw  = (const float*)d_in[7];
  const float* vb  = (const float*)d_in[8];
  const float* aow = (const float*)d_in[9];
  const float* aob = (const float*)d_in[10];
  const float* qnw = (const float*)d_in[11];
  const float* qnb = (const float*)d_in[12];
  const float* tnw = (const float*)d_in[13];
  const float* tnb = (const float*)d_in[14];
  const float* onw = (const float*)d_in[15];
  const float* onb = (const float*)d_in[16];
  const float* opw = (const float*)d_in[17];
  const float* opb = (const float*)d_in[18];
  const float* bpw1 = (const float*)d_in[19];
  const float* bpb1 = (const float*)d_in[20];
  const float* bpw2 = (const float*)d_in[21];
  const float* bpb2 = (const float*)d_in[22];
  const float* apw1 = (const float*)d_in[23];
  const float* apb1 = (const float*)d_in[24];
  const float* apw2 = (const float*)d_in[25];
  const float* apb2 = (const float*)d_in[26];
  const float* gw1 = (const float*)d_in[27];
  const float* gb1 = (const float*)d_in[28];
  const float* gw2 = (const float*)d_in[29];
  const float* gb2 = (const float*)d_in[30];
  float* out = (float*)d_out;

  if (ws_size < WS_NEED) return;
  char* ws = (char*)d_ws;
  float* bev   = (float*)(ws + B_BEV);
  float* score = (float*)(ws + B_SCORE);
  int*   idx   = (int*)(ws + B_IDX);
  short* wbf   = (short*)(ws + B_WBF);
  __hip_bfloat16* kvb = (__hip_bfloat16*)(ws + B_KV);
  short* Kgb  = (short*)(ws + B_KG);
  short* Vgb  = (short*)(ws + B_VG);
  short* Vtb  = (short*)(ws + B_VT);
  short* h1b  = (short*)(ws + B_H1);
  float* qi32 = (float*)(ws + B_QI32);
  short* qi16 = (short*)(ws + B_QI16);
  short* qryb = (short*)(ws + B_QUERY);
  short* Qgb  = (short*)(ws + B_QG);
  short* ctxb = (short*)(ws + B_CTX);
  short* aobuf = (short*)(ws + B_AO);
  float* opo  = (float*)(ws + B_OPO);
  float* lc   = (float*)(ws + B_LC);
  short* g1b  = (short*)(ws + B_G1);

  wconv_kernel<<<7168, 256, 0, stream>>>(qw, kw, vw, aow, opw, apw2, gw1, gw2,
                                         (__hip_bfloat16*)wbf);
  pool_kernel<<<BB * DKV * HW / 256, 256, 0, stream>>>(pts, bev);
  score_kernel<<<BB * HW / 256, 256, 0, stream>>>(bev, score);
  topk_kernel<<<BB, 1024, 0, stream>>>(score, idx);
  token_kernel<<<BB * KT, 256, 0, stream>>>(bev, idx, bpw1, bpb1, bpw2, bpb2, tnw, tnb, kvb);
  // K/V projections (M=1024, N=512, K=256)
  mgemm<0><<<dim3(8, 8), 256, 0, stream>>>((const short*)kvb, wbf + WO_KW, kb,
                                           nullptr, nullptr, Kgb, nullptr, 1024, 512, 256);
  mgemm<0><<<dim3(8, 8), 256, 0, stream>>>((const short*)kvb, wbf + WO_VW, vb,
                                           nullptr, nullptr, Vgb, nullptr, 1024, 512, 256);
  vtrans_kernel<<<dim3(4, 8, BB), 256, 0, stream>>>(Vgb, Vtb);
  ap1_kernel<<<MR * 512 / 256, 256, 0, stream>>>(anchor, apw1, apb1, (__hip_bfloat16*)h1b);
  // qi = inst + h1 @ apw2^T + apb2 (f32 + bf16)
  mgemm<1><<<dim3(8, 20), 256, 0, stream>>>(h1b, wbf + WO_APW2, apb2, inst, nullptr,
                                            qi32, qi16, MR, 512, 512);
  ln512_kernel<1><<<MR, 256, 0, stream>>>(qi32, qryb, qnw, qnb);
  // Q = (query @ qw^T + qb) * 0.125
  mgemm<3><<<dim3(8, 20), 256, 0, stream>>>(qryb, wbf + WO_QW, qb, nullptr, nullptr,
                                            Qgb, nullptr, MR, 512, 512);
  attn_kernel<<<156, 256, 0, stream>>>(Qgb, Kgb, Vtb, (__hip_bfloat16*)ctxb);
  // ao = ctx @ aow^T + aob
  mgemm<0><<<dim3(8, 20), 256, 0, stream>>>(ctxb, wbf + WO_AOW, aob, nullptr, nullptr,
                                            aobuf, nullptr, MR, 512, 512);
  // opo = ao @ opw^T + opb (f32)
  mgemm<4><<<dim3(8, 20), 256, 0, stream>>>(aobuf, wbf + WO_OPW, opb, nullptr, nullptr,
                                            opo, nullptr, MR, 512, 512);
  ln512_kernel<0><<<MR, 256, 0, stream>>>(opo, lc, onw, onb);
  // g1 = relu(qi @ gw1^T + gb1)
  mgemm<2><<<dim3(8, 20), 256, 0, stream>>>(qi16, wbf + WO_GW1, gb1, nullptr, nullptr,
                                            g1b, nullptr, MR, 512, 512);
  // out = inst + sigmoid(g1 @ gw2^T + gb2) * lc
  mgemm<5><<<dim3(8, 20), 256, 0, stream>>>(g1b, wbf + WO_GW2, gb2, inst, lc,
                                            out, nullptr, MR, 512, 512);
}

// Round 8
// 331.153 us; speedup vs baseline: 1.1515x; 1.1515x over previous
//
#include <hip/hip_runtime.h>
#include <hip/hip_bf16.h>
#include <math.h>

constexpr int BB  = 2;
constexpr int NN  = 1220;
constexpr int DKV = 256;
constexpr int H0  = 512, W0 = 512;
constexpr int HH  = 128, WW = 128;
constexpr int HW  = HH * WW;      // 16384
constexpr int KT  = 512;
constexpr int MR  = BB * NN;      // 2440

typedef __attribute__((ext_vector_type(8)))  short bf16x8;
typedef __attribute__((ext_vector_type(4)))  float f32x4;
typedef __attribute__((ext_vector_type(16))) float f32x16;

// ---- workspace byte offsets (256-aligned) ----
constexpr size_t B_BEV   = 0;            // f32 bev [B][C][HW] : 33,554,432
constexpr size_t B_SCORE = 33554432;     // f32 score          : 131,072
constexpr size_t B_IDX   = 33685504;     // int idx            : 4,096
constexpr size_t B_WBF   = 33689600;     // bf16 weights       : 3,670,016
constexpr size_t B_KV    = 37359616;     // kv bf16 [1024][256]: 524,288
constexpr size_t B_KG    = 37883904;     // K bf16 [1024][512] : 1,048,576
constexpr size_t B_VG    = 38932480;     // V bf16             : 1,048,576
constexpr size_t B_VT    = 39981056;     // V^T bf16 [2][8][64][512]
constexpr size_t B_H1    = 41029632;     // h1 bf16 [2560][512]
constexpr size_t B_QI32  = 43651072;     // qi f32 [2560][512]
constexpr size_t B_QI16  = 48893952;     // qi bf16
constexpr size_t B_QUERY = 51515392;     // LN(qi) bf16
constexpr size_t B_QG    = 54136832;     // Q bf16 (pre-scaled)
constexpr size_t B_CTX   = 56758272;     // ctx bf16
constexpr size_t B_AO    = 59379712;     // ao bf16
constexpr size_t B_OPO   = 62001152;     // opo f32
constexpr size_t B_LC    = 67244032;     // lc f32
constexpr size_t B_G1    = 72486912;     // g1 bf16
constexpr size_t WS_NEED = 75112448;

constexpr size_t WO_QW = 0, WO_KW = 262144, WO_VW = 393216, WO_AOW = 524288,
                 WO_OPW = 786432, WO_APW2 = 1048576, WO_GW1 = 1310720, WO_GW2 = 1572864;

__device__ __forceinline__ void gload_lds16(void* lds, const void* g) {
  __builtin_amdgcn_global_load_lds((const __attribute__((address_space(1))) unsigned int*)g,
                                   (__attribute__((address_space(3))) unsigned int*)lds, 16, 0, 0);
}

__device__ __forceinline__ unsigned cvt_pk_bf16(float a, float b) {
  unsigned r;
  asm("v_cvt_pk_bf16_f32 %0, %1, %2" : "=v"(r) : "v"(a), "v"(b));
  return r;
}

// ---------------- weight f32 -> bf16 ----------------
__global__ __launch_bounds__(256) void wconv_kernel(
    const float* __restrict__ qw, const float* __restrict__ kw,
    const float* __restrict__ vw, const float* __restrict__ aow,
    const float* __restrict__ opw, const float* __restrict__ apw2,
    const float* __restrict__ gw1, const float* __restrict__ gw2,
    __hip_bfloat16* __restrict__ dst) {
  int i = blockIdx.x * 256 + threadIdx.x;      // < 1835008
  const float* src; int off;
  if (i < 262144)       { src = qw;   off = 0; }
  else if (i < 393216)  { src = kw;   off = 262144; }
  else if (i < 524288)  { src = vw;   off = 393216; }
  else if (i < 786432)  { src = aow;  off = 524288; }
  else if (i < 1048576) { src = opw;  off = 786432; }
  else if (i < 1310720) { src = apw2; off = 1048576; }
  else if (i < 1572864) { src = gw1;  off = 1310720; }
  else                  { src = gw2;  off = 1572864; }
  dst[i] = __float2bfloat16(src[i - off]);
}

// ---------------- avg_pool2d 4x4 (EXACT R3) ----------------
__global__ __launch_bounds__(256) void pool_kernel(const float* __restrict__ pts,
                                                   float* __restrict__ bev) {
  int o = blockIdx.x * 256 + threadIdx.x;
  int w  = o & (WW - 1);
  int h  = (o >> 7) & (HH - 1);
  int bc = o >> 14;
  const float* p = pts + ((bc * H0) + h * 4) * W0 + w * 4;
  float s = 0.f;
#pragma unroll
  for (int r = 0; r < 4; ++r) {
    float4 v = *(const float4*)(p + r * W0);
    s += v.x + v.y + v.z + v.w;
  }
  bev[o] = s * (1.f / 16.f);
}

// ---------------- score (EXACT R3) ----------------
__global__ __launch_bounds__(256) void score_kernel(const float* __restrict__ bev,
                                                    float* __restrict__ score) {
  int t = blockIdx.x * 256 + threadIdx.x;
  int b = t >> 14, p = t & (HW - 1);
  const float* base = bev + (size_t)(b * DKV) * HW + p;
  float acc = 0.f;
  for (int c = 0; c < DKV; ++c) {
    float v = base[c * HW];
    acc += v * v;
  }
  score[t] = acc * (1.f / DKV);
}

// ---------------- top-K set, radix select (BISECT: parallel tie-scan) ----------
__global__ __launch_bounds__(1024) void topk_kernel(const float* __restrict__ score,
                                                    int* __restrict__ idx) {
  int b = blockIdx.x;
  const float* s = score + b * HW;
  __shared__ int hist[16][256];
  __shared__ int htot[256];
  __shared__ int pscan[1024];
  __shared__ int sh_digit, sh_need, sh_cnt;
  int tid = threadIdx.x;
  int wv = tid >> 6;
  unsigned prefix = 0;
  int need = KT;
  for (int pass = 0; pass < 4; ++pass) {
    int shift = 24 - pass * 8;
    if (tid < 256) {
#pragma unroll
      for (int w = 0; w < 16; ++w) hist[w][tid] = 0;
    }
    __syncthreads();
    for (int p = tid; p < HW; p += 1024) {
      unsigned u = __float_as_uint(s[p]);
      bool match = (pass == 0) || ((u >> (shift + 8)) == prefix);
      if (match) atomicAdd(&hist[wv][(u >> shift) & 255], 1);
    }
    __syncthreads();
    if (tid < 256) {
      int t = 0;
#pragma unroll
      for (int w = 0; w < 16; ++w) t += hist[w][tid];
      htot[tid] = t;
    }
    __syncthreads();
    for (int off = 1; off < 256; off <<= 1) {
      int v = 0;
      if (tid < 256) v = htot[tid] + ((tid + off < 256) ? htot[tid + off] : 0);
      __syncthreads();
      if (tid < 256) htot[tid] = v;
      __syncthreads();
    }
    if (tid < 256) {
      int sfx = htot[tid], sfx1 = (tid < 255) ? htot[tid + 1] : 0;
      if (sfx >= need && sfx1 < need) { sh_digit = tid; sh_need = need - sfx1; }
    }
    __syncthreads();
    prefix = (prefix << 8) | (unsigned)sh_digit;
    need = sh_need;
    __syncthreads();
  }
  unsigned T = prefix;
  int r = need;
  if (tid == 0) sh_cnt = 0;
  __syncthreads();
  for (int p = tid; p < HW; p += 1024) {
    if (__float_as_uint(s[p]) > T) {
      int pos = atomicAdd(&sh_cnt, 1);
      idx[b * KT + pos] = p;
    }
  }
  __syncthreads();
  int base = sh_cnt;                           // == KT - r
  // parallel ordered tie selection (smallest indices among score == T)
  int base0 = tid * 16;
  int cnt = 0;
#pragma unroll
  for (int j = 0; j < 16; ++j) cnt += (__float_as_uint(s[base0 + j]) == T);
  pscan[tid] = cnt;
  __syncthreads();
  for (int off = 1; off < 1024; off <<= 1) {
    int v = pscan[tid];
    int add = (tid >= off) ? pscan[tid - off] : 0;
    __syncthreads();
    pscan[tid] = v + add;
    __syncthreads();
  }
  int rank = pscan[tid] - cnt;                 // exclusive prefix (index order)
  for (int j = 0; j < 16 && rank < r; ++j) {
    int p = base0 + j;
    if (__float_as_uint(s[p]) == T) {
      idx[b * KT + base + rank] = p;
      ++rank;
    }
  }
}

// ---------------- token gather + bev_pos_mlp + LN(tn) -> kv bf16 ----------------
__global__ __launch_bounds__(256) void token_kernel(const float* __restrict__ bev,
    const int* __restrict__ idx,
    const float* __restrict__ bw1, const float* __restrict__ bb1,
    const float* __restrict__ bw2, const float* __restrict__ bb2,
    const float* __restrict__ tw, const float* __restrict__ tb,
    __hip_bfloat16* __restrict__ kv) {
  int blk = blockIdx.x;
  int b = blk >> 9;
  int c = threadIdx.x;
  int p = idx[blk];
  float val = bev[((size_t)(b * DKV + c) << 14) + p];
  float px = ((p & (WW - 1)) + 0.5f) * (1.f / WW);
  float py = ((p >> 7) + 0.5f) * (1.f / HH);
  __shared__ float h1[DKV];
  __shared__ float red[DKV];
  h1[c] = fmaxf(bw1[c * 2] * px + bw1[c * 2 + 1] * py + bb1[c], 0.f);
  __syncthreads();
  float o = bb2[c];
  const float4* w4 = (const float4*)(bw2 + c * DKV);
#pragma unroll 4
  for (int j = 0; j < DKV / 4; ++j) {
    float4 w = w4[j];
    o += w.x * h1[j * 4] + w.y * h1[j * 4 + 1] + w.z * h1[j * 4 + 2] + w.w * h1[j * 4 + 3];
  }
  float tokv = val + o;
  red[c] = tokv; __syncthreads();
  for (int st = 128; st > 0; st >>= 1) { if (c < st) red[c] += red[c + st]; __syncthreads(); }
  float mean = red[0] * (1.f / DKV);
  __syncthreads();
  float d = tokv - mean;
  red[c] = d * d; __syncthreads();
  for (int st = 128; st > 0; st >>= 1) { if (c < st) red[c] += red[c + st]; __syncthreads(); }
  float inv = rsqrtf(red[0] * (1.f / DKV) + 1e-5f);
  kv[(size_t)blk * DKV + c] = __float2bfloat16(d * inv * tw[c] + tb[c]);
}

// ---------------- anchor xy + ap layer1 (relu) -> bf16 ----------------
__global__ __launch_bounds__(256) void ap1_kernel(const float* __restrict__ anchor,
    const float* __restrict__ w1, const float* __restrict__ b1,
    __hip_bfloat16* __restrict__ h) {
  int g = blockIdx.x * 256 + threadIdx.x;
  int row = g >> 9, col = g & 511;
  float ax = anchor[row * 11 + 0];
  float ay = anchor[row * 11 + 1];
  float xr = fminf(fmaxf((ax + 51.2f) * (1.f / 102.4f), 0.f), 1.f);
  float yr = fminf(fmaxf((ay + 51.2f) * (1.f / 102.4f), 0.f), 1.f);
  h[g] = __float2bfloat16(fmaxf(w1[col * 2] * xr + w1[col * 2 + 1] * yr + b1[col], 0.f));
}

// ---------------- MFMA GEMM: C = A(bf16) @ W(bf16)^T + bias ----------------
// BM=64, BN=64, BK=64, 4 waves (2x2 quadrants); double-buffered LDS.
// Grid: (N/64, ceil(M/64)) -> 312 blocks for M=2440 (full CU coverage).
template <int EPI>
__global__ __launch_bounds__(256) void mgemm(
    const short* __restrict__ A, const short* __restrict__ W,
    const float* __restrict__ bias, const float* __restrict__ aux1,
    const float* __restrict__ aux2, void* __restrict__ o1, void* __restrict__ o2,
    int M, int Nd, int Kd) {
  __shared__ short As[2][64 * 64];
  __shared__ short Bs[2][64 * 64];
  const int tid = threadIdx.x;
  const int wave = tid >> 6, lane = tid & 63;
  const int m0 = blockIdx.y * 64, n0 = blockIdx.x * 64;
  const int wr = wave >> 1, wc = wave & 1;
  const int srow = lane >> 3, sslot = lane & 7;
  const int ss = sslot ^ srow;              // involution swizzle on 16B slots
  f32x4 acc[2][2];
#pragma unroll
  for (int i = 0; i < 2; ++i)
#pragma unroll
    for (int j = 0; j < 2; ++j) acc[i][j] = (f32x4){0.f, 0.f, 0.f, 0.f};

  const short* Abase = A + (size_t)(m0 + srow) * Kd + ss * 8;
  const short* Wbase = W + (size_t)(n0 + srow) * Kd + ss * 8;
  const int nk = Kd >> 6;

#define STAGE(buf, k0)                                                        \
  {                                                                           \
    _Pragma("unroll")                                                         \
    for (int u = 0; u < 2; ++u) {                                             \
      int unit = wave * 2 + u;                                                \
      gload_lds16(&As[buf][unit * 512], Abase + (size_t)(unit * 8) * Kd + (k0)); \
      gload_lds16(&Bs[buf][unit * 512], Wbase + (size_t)(unit * 8) * Kd + (k0)); \
    }                                                                         \
  }

  STAGE(0, 0);
  __syncthreads();
  for (int t = 0; t < nk; ++t) {
    if (t + 1 < nk) STAGE((t + 1) & 1, (t + 1) << 6);
    const short* as = As[t & 1];
    const short* bs = Bs[t & 1];
#pragma unroll
    for (int ks = 0; ks < 2; ++ks) {
      bf16x8 af[2], bf[2];
#pragma unroll
      for (int mf = 0; mf < 2; ++mf) {
        int rr = wr * 32 + mf * 16 + (lane & 15);
        int slot = (ks * 4 + (lane >> 4)) ^ (rr & 7);
        af[mf] = *(const bf16x8*)(as + rr * 64 + slot * 8);
      }
#pragma unroll
      for (int nf = 0; nf < 2; ++nf) {
        int rr = wc * 32 + nf * 16 + (lane & 15);
        int slot = (ks * 4 + (lane >> 4)) ^ (rr & 7);
        bf[nf] = *(const bf16x8*)(bs + rr * 64 + slot * 8);
      }
#pragma unroll
      for (int mf = 0; mf < 2; ++mf)
#pragma unroll
        for (int nf = 0; nf < 2; ++nf)
          acc[mf][nf] = __builtin_amdgcn_mfma_f32_16x16x32_bf16(af[mf], bf[nf], acc[mf][nf], 0, 0, 0);
    }
    __syncthreads();
  }
#undef STAGE
#pragma unroll
  for (int mf = 0; mf < 2; ++mf)
#pragma unroll
    for (int nf = 0; nf < 2; ++nf) {
      int col = n0 + wc * 32 + nf * 16 + (lane & 15);
      float bv = bias[col];
#pragma unroll
      for (int i = 0; i < 4; ++i) {
        int row = m0 + wr * 32 + mf * 16 + (lane >> 4) * 4 + i;
        if (row < M) {
          float v = acc[mf][nf][i] + bv;
          size_t off = (size_t)row * Nd + col;
          if (EPI == 0) ((__hip_bfloat16*)o1)[off] = __float2bfloat16(v);
          else if (EPI == 1) {
            v += aux1[off];
            ((float*)o1)[off] = v;
            ((__hip_bfloat16*)o2)[off] = __float2bfloat16(v);
          } else if (EPI == 2) ((__hip_bfloat16*)o1)[off] = __float2bfloat16(fmaxf(v, 0.f));
          else if (EPI == 3) ((__hip_bfloat16*)o1)[off] = __float2bfloat16(v * 0.125f);
          else if (EPI == 4) ((float*)o1)[off] = v;
          else if (EPI == 5) {
            float g = 1.f / (1.f + __expf(-v));
            ((float*)o1)[off] = aux1[off] + g * aux2[off];
          }
        }
      }
    }
}

// ---------------- LayerNorm D=512 ----------------
template <int OUT_BF16>
__global__ __launch_bounds__(256) void ln512_kernel(const float* __restrict__ in,
    void* __restrict__ outp, const float* __restrict__ w, const float* __restrict__ bb) {
  int row = blockIdx.x, tid = threadIdx.x;
  float x0 = in[(size_t)row * 512 + tid];
  float x1 = in[(size_t)row * 512 + 256 + tid];
  __shared__ float rs[256], rq[256];
  rs[tid] = x0 + x1;
  rq[tid] = x0 * x0 + x1 * x1;
  __syncthreads();
  for (int o = 128; o > 0; o >>= 1) {
    if (tid < o) { rs[tid] += rs[tid + o]; rq[tid] += rq[tid + o]; }
    __syncthreads();
  }
  float mean = rs[0] * (1.f / 512.f);
  float var = rq[0] * (1.f / 512.f) - mean * mean;
  float inv = rsqrtf(var + 1e-5f);
  float y0 = (x0 - mean) * inv * w[tid] + bb[tid];
  float y1 = (x1 - mean) * inv * w[256 + tid] + bb[256 + tid];
  if (OUT_BF16) {
    ((__hip_bfloat16*)outp)[(size_t)row * 512 + tid] = __float2bfloat16(y0);
    ((__hip_bfloat16*)outp)[(size_t)row * 512 + 256 + tid] = __float2bfloat16(y1);
  } else {
    ((float*)outp)[(size_t)row * 512 + tid] = y0;
    ((float*)outp)[(size_t)row * 512 + 256 + tid] = y1;
  }
}

// ---------------- V transpose: [b*512+t][h*64+d] -> [b][h][d][t] ----------------
__global__ __launch_bounds__(256) void vtrans_kernel(const short* __restrict__ V,
                                                     short* __restrict__ Vt) {
  __shared__ short tile[128][72];
  int tc = blockIdx.x, h = blockIdx.y, b = blockIdx.z;
  int tid = threadIdx.x;
#pragma unroll
  for (int it = 0; it < 8; ++it) {
    int e = it * 256 + tid;
    int r = e >> 4, c = (e & 15) * 4;
    *(short4*)&tile[r][c] =
        *(const short4*)(V + ((size_t)(b * 512 + tc * 128 + r)) * 512 + h * 64 + c);
  }
  __syncthreads();
#pragma unroll
  for (int it = 0; it < 8; ++it) {
    int e = it * 256 + tid;
    int d = e >> 5, t4 = (e & 31) * 4;
    short4 v;
    v.x = tile[t4 + 0][d]; v.y = tile[t4 + 1][d];
    v.z = tile[t4 + 2][d]; v.w = tile[t4 + 3][d];
    *(short4*)(Vt + (((size_t)(b * 8 + h)) * 64 + d) * 512 + tc * 128 + t4) = v;
  }
}

// ---------------- flash attention (EXACT R3 launch: 4 waves/block) ----------------
__global__ __launch_bounds__(256) void attn_kernel(
    const short* __restrict__ Qg, const short* __restrict__ Kg,
    const short* __restrict__ Vt, __hip_bfloat16* __restrict__ ctx) {
  int tid = threadIdx.x;
  int wid = blockIdx.x * 4 + (tid >> 6);     // 0..623
  int lane = tid & 63;
  int l31 = lane & 31, lhi = lane >> 5;
  int qc = wid % 39;
  int bh = wid / 39;
  int h = bh & 7, b = bh >> 3;
  int n = qc * 32 + l31;
  size_t qrow = (size_t)b * NN + n;          // < 2560 rows
  const short* qp = Qg + qrow * 512 + h * 64 + lhi * 8;
  bf16x8 qf0 = *(const bf16x8*)(qp);
  bf16x8 qf1 = *(const bf16x8*)(qp + 16);
  bf16x8 qf2 = *(const bf16x8*)(qp + 32);
  bf16x8 qf3 = *(const bf16x8*)(qp + 48);
  f32x16 ot0 = {}, ot1 = {};
  float m_run = -1e30f, lsum = 0.f;
  const short* kbase = Kg + ((size_t)(b * KT) + l31) * 512 + h * 64 + lhi * 8;
  const short* vbase = Vt + (((size_t)(b * 8 + h)) * 64 + l31) * 512 + lhi * 8;
  for (int tc = 0; tc < 16; ++tc) {
    const short* kp = kbase + (size_t)(tc * 32) * 512;
    bf16x8 kf0 = *(const bf16x8*)(kp);
    bf16x8 kf1 = *(const bf16x8*)(kp + 16);
    bf16x8 kf2 = *(const bf16x8*)(kp + 32);
    bf16x8 kf3 = *(const bf16x8*)(kp + 48);
    const short* vp = vbase + tc * 32;
    bf16x8 v00 = *(const bf16x8*)(vp);
    bf16x8 v01 = *(const bf16x8*)(vp + 16);
    bf16x8 v10 = *(const bf16x8*)(vp + 32 * 512);
    bf16x8 v11 = *(const bf16x8*)(vp + 32 * 512 + 16);
    f32x16 s = {};
    s = __builtin_amdgcn_mfma_f32_32x32x16_bf16(kf0, qf0, s, 0, 0, 0);
    s = __builtin_amdgcn_mfma_f32_32x32x16_bf16(kf1, qf1, s, 0, 0, 0);
    s = __builtin_amdgcn_mfma_f32_32x32x16_bf16(kf2, qf2, s, 0, 0, 0);
    s = __builtin_amdgcn_mfma_f32_32x32x16_bf16(kf3, qf3, s, 0, 0, 0);
    float pmax = s[0];
#pragma unroll
    for (int i = 1; i < 16; ++i) pmax = fmaxf(pmax, s[i]);
    pmax = fmaxf(pmax, __shfl_xor(pmax, 32));
    float m_new = fmaxf(m_run, pmax);
    float corr = __expf(m_run - m_new);
    m_run = m_new;
    lsum *= corr;
#pragma unroll
    for (int i = 0; i < 16; ++i) { ot0[i] *= corr; ot1[i] *= corr; }
    float p[16];
    float psum = 0.f;
#pragma unroll
    for (int i = 0; i < 16; ++i) { p[i] = __expf(s[i] - m_new); psum += p[i]; }
    lsum += psum;
    unsigned w0 = cvt_pk_bf16(p[0], p[1]),   w1 = cvt_pk_bf16(p[2], p[3]);
    unsigned w2 = cvt_pk_bf16(p[4], p[5]),   w3 = cvt_pk_bf16(p[6], p[7]);
    unsigned w4 = cvt_pk_bf16(p[8], p[9]),   w5 = cvt_pk_bf16(p[10], p[11]);
    unsigned w6 = cvt_pk_bf16(p[12], p[13]), w7 = cvt_pk_bf16(p[14], p[15]);
    unsigned sw0 = (unsigned)__shfl_xor((int)w0, 32), sw1 = (unsigned)__shfl_xor((int)w1, 32);
    unsigned sw2 = (unsigned)__shfl_xor((int)w2, 32), sw3 = (unsigned)__shfl_xor((int)w3, 32);
    unsigned sw4 = (unsigned)__shfl_xor((int)w4, 32), sw5 = (unsigned)__shfl_xor((int)w5, 32);
    unsigned sw6 = (unsigned)__shfl_xor((int)w6, 32), sw7 = (unsigned)__shfl_xor((int)w7, 32);
    union UU { unsigned u[4]; bf16x8 v; };
    UU ub0, ub1;
    ub0.u[0] = lhi ? sw2 : w0; ub0.u[1] = lhi ? sw3 : w1;
    ub0.u[2] = lhi ? w2 : sw0; ub0.u[3] = lhi ? w3 : sw1;
    ub1.u[0] = lhi ? sw6 : w4; ub1.u[1] = lhi ? sw7 : w5;
    ub1.u[2] = lhi ? w6 : sw4; ub1.u[3] = lhi ? w7 : sw5;
    ot0 = __builtin_amdgcn_mfma_f32_32x32x16_bf16(v00, ub0.v, ot0, 0, 0, 0);
    ot0 = __builtin_amdgcn_mfma_f32_32x32x16_bf16(v01, ub1.v, ot0, 0, 0, 0);
    ot1 = __builtin_amdgcn_mfma_f32_32x32x16_bf16(v10, ub0.v, ot1, 0, 0, 0);
    ot1 = __builtin_amdgcn_mfma_f32_32x32x16_bf16(v11, ub1.v, ot1, 0, 0, 0);
  }
  lsum += __shfl_xor(lsum, 32);
  float inv = 1.f / lsum;
  if (n < NN) {
    __hip_bfloat16* cp = ctx + qrow * 512 + h * 64;
#pragma unroll
    for (int r = 0; r < 16; ++r) {
      int d = (r & 3) + 8 * (r >> 2) + 4 * lhi;
      cp[d]      = __float2bfloat16(ot0[r] * inv);
      cp[32 + d] = __float2bfloat16(ot1[r] * inv);
    }
  }
}

extern "C" void kernel_launch(void* const* d_in, const int* in_sizes, int n_in,
                              void* d_out, int out_size, void* d_ws, size_t ws_size,
                              hipStream_t stream) {
  const float* inst   = (const float*)d_in[0];
  const float* pts    = (const float*)d_in[1];
  const float* anchor = (const float*)d_in[2];
  const float* qw  = (const float*)d_in[3];
  const float* qb  = (const float*)d_in[4];
  const float* kw  = (const float*)d_in[5];
  const float* kb  = (const float*)d_in[6];
  const float* vw  = (const float*)d_in[7];
  const float* vb  = (const float*)d_in[8];
  const float* aow = (const float*)d_in[9];
  const float* aob = (const float*)d_in[10];
  const float* qnw = (const float*)d_in[11];
  const float* qnb = (const float*)d_in[12];
  const float* tnw = (const float*)d_in[13];
  const float* tnb = (const float*)d_in[14];
  const float* onw = (const float*)d_in[15];
  const float* onb = (const float*)d_in[16];
  const float* opw = (const float*)d_in[17];
  const float* opb = (const float*)d_in[18];
  const float* bpw1 = (const float*)d_in[19];
  const float* bpb1 = (const float*)d_in[20];
  const float* bpw2 = (const float*)d_in[21];
  const float* bpb2 = (const float*)d_in[22];
  const float* apw1 = (const float*)d_in[23];
  const float* apb1 = (const float*)d_in[24];
  const float* apw2 = (const float*)d_in[25];
  const float* apb2 = (const float*)d_in[26];
  const float* gw1 = (const float*)d_in[27];
  const float* gb1 = (const float*)d_in[28];
  const float* gw2 = (const float*)d_in[29];
  const float* gb2 = (const float*)d_in[30];
  float* out = (float*)d_out;

  if (ws_size < WS_NEED) return;
  char* ws = (char*)d_ws;
  float* bev   = (float*)(ws + B_BEV);
  float* score = (float*)(ws + B_SCORE);
  int*   idx   = (int*)(ws + B_IDX);
  short* wbf   = (short*)(ws + B_WBF);
  __hip_bfloat16* kvb = (__hip_bfloat16*)(ws + B_KV);
  short* Kgb  = (short*)(ws + B_KG);
  short* Vgb  = (short*)(ws + B_VG);
  short* Vtb  = (short*)(ws + B_VT);
  short* h1b  = (short*)(ws + B_H1);
  float* qi32 = (float*)(ws + B_QI32);
  short* qi16 = (short*)(ws + B_QI16);
  short* qryb = (short*)(ws + B_QUERY);
  short* Qgb  = (short*)(ws + B_QG);
  short* ctxb = (short*)(ws + B_CTX);
  short* aobuf = (short*)(ws + B_AO);
  float* opo  = (float*)(ws + B_OPO);
  float* lc   = (float*)(ws + B_LC);
  short* g1b  = (short*)(ws + B_G1);

  wconv_kernel<<<7168, 256, 0, stream>>>(qw, kw, vw, aow, opw, apw2, gw1, gw2,
                                         (__hip_bfloat16*)wbf);
  pool_kernel<<<BB * DKV * HW / 256, 256, 0, stream>>>(pts, bev);
  score_kernel<<<BB * HW / 256, 256, 0, stream>>>(bev, score);
  topk_kernel<<<BB, 1024, 0, stream>>>(score, idx);
  token_kernel<<<BB * KT, 256, 0, stream>>>(bev, idx, bpw1, bpb1, bpw2, bpb2, tnw, tnb, kvb);
  // K/V projections (M=1024, N=512, K=256)
  mgemm<0><<<dim3(8, 16), 256, 0, stream>>>((const short*)kvb, wbf + WO_KW, kb,
                                            nullptr, nullptr, Kgb, nullptr, 1024, 512, 256);
  mgemm<0><<<dim3(8, 16), 256, 0, stream>>>((const short*)kvb, wbf + WO_VW, vb,
                                            nullptr, nullptr, Vgb, nullptr, 1024, 512, 256);
  vtrans_kernel<<<dim3(4, 8, BB), 256, 0, stream>>>(Vgb, Vtb);
  ap1_kernel<<<MR * 512 / 256, 256, 0, stream>>>(anchor, apw1, apb1, (__hip_bfloat16*)h1b);
  // qi = inst + h1 @ apw2^T + apb2 (f32 + bf16)
  mgemm<1><<<dim3(8, 39), 256, 0, stream>>>(h1b, wbf + WO_APW2, apb2, inst, nullptr,
                                            qi32, qi16, MR, 512, 512);
  ln512_kernel<1><<<MR, 256, 0, stream>>>(qi32, qryb, qnw, qnb);
  // Q = (query @ qw^T + qb) * 0.125
  mgemm<3><<<dim3(8, 39), 256, 0, stream>>>(qryb, wbf + WO_QW, qb, nullptr, nullptr,
                                            Qgb, nullptr, MR, 512, 512);
  attn_kernel<<<156, 256, 0, stream>>>(Qgb, Kgb, Vtb, (__hip_bfloat16*)ctxb);
  // ao = ctx @ aow^T + aob
  mgemm<0><<<dim3(8, 39), 256, 0, stream>>>(ctxb, wbf + WO_AOW, aob, nullptr, nullptr,
                                            aobuf, nullptr, MR, 512, 512);
  // opo = ao @ opw^T + opb (f32)
  mgemm<4><<<dim3(8, 39), 256, 0, stream>>>(aobuf, wbf + WO_OPW, opb, nullptr, nullptr,
                                            opo, nullptr, MR, 512, 512);
  ln512_kernel<0><<<MR, 256, 0, stream>>>(opo, lc, onw, onb);
  // g1 = relu(qi @ gw1^T + gb1)
  mgemm<2><<<dim3(8, 39), 256, 0, stream>>>(qi16, wbf + WO_GW1, gb1, nullptr, nullptr,
                                            g1b, nullptr, MR, 512, 512);
  // out = inst + sigmoid(g1 @ gw2^T + gb2) * lc
  mgemm<5><<<dim3(8, 39), 256, 0, stream>>>(g1b, wbf + WO_GW2, gb2, inst, lc,
                                            out, nullptr, MR, 512, 512);
}